// Round 1
// baseline (156.161 us; speedup 1.0000x reference)
//
#include <hip/hip_runtime.h>

#define TPB 256

__device__ __forceinline__ float fast_rcp(float x) { return __builtin_amdgcn_rcpf(x); }
__device__ __forceinline__ float sigm(float x) { return fast_rcp(1.0f + __expf(-x)); }
__device__ __forceinline__ float ftanh(float x) { return 1.0f - 2.0f * fast_rcp(__expf(2.0f * x) + 1.0f); }

// GRU step with weights resident in SGPRs (wave-uniform global loads, constant
// indices). The h-independent side (gi, plus the r/z gate's bhh) is computed
// off the critical path; h-update uses a single dependent fma after n:
//   h_new = n*(1-z) + z*h   with (1-z) and z*h computed while n is in flight.
#define GRU_STEP(WIH, WHH, BIH, BHH, X0, X1, H0, H1)                          \
  {                                                                            \
    const float x0_ = (X0), x1_ = (X1);                                        \
    float pre0 = fmaf(WIH[0], x0_, fmaf(WIH[1], x1_, BIH[0] + BHH[0]));        \
    float pre1 = fmaf(WIH[2], x0_, fmaf(WIH[3], x1_, BIH[1] + BHH[1]));        \
    float pre2 = fmaf(WIH[4], x0_, fmaf(WIH[5], x1_, BIH[2] + BHH[2]));        \
    float pre3 = fmaf(WIH[6], x0_, fmaf(WIH[7], x1_, BIH[3] + BHH[3]));        \
    float gin0 = fmaf(WIH[8], x0_, fmaf(WIH[9], x1_, BIH[4]));                 \
    float gin1 = fmaf(WIH[10], x0_, fmaf(WIH[11], x1_, BIH[5]));               \
    float r0 = sigm(fmaf(WHH[0], H0, fmaf(WHH[1], H1, pre0)));                 \
    float r1 = sigm(fmaf(WHH[2], H0, fmaf(WHH[3], H1, pre1)));                 \
    float z0 = sigm(fmaf(WHH[4], H0, fmaf(WHH[5], H1, pre2)));                 \
    float z1 = sigm(fmaf(WHH[6], H0, fmaf(WHH[7], H1, pre3)));                 \
    float ghn0 = fmaf(WHH[8], H0, fmaf(WHH[9], H1, BHH[4]));                   \
    float ghn1 = fmaf(WHH[10], H0, fmaf(WHH[11], H1, BHH[5]));                 \
    float n0 = ftanh(fmaf(r0, ghn0, gin0));                                    \
    float n1 = ftanh(fmaf(r1, ghn1, gin1));                                    \
    float omz0 = 1.0f - z0, zh0 = z0 * (H0);                                   \
    float omz1 = 1.0f - z1, zh1 = z1 * (H1);                                   \
    H0 = fmaf(n0, omz0, zh0);                                                  \
    H1 = fmaf(n1, omz1, zh1);                                                  \
  }

__global__ __launch_bounds__(TPB) void rec_policy_kernel(
    const float* __restrict__ x,
    const float* __restrict__ up_wih, const float* __restrict__ up_whh,
    const float* __restrict__ up_bih, const float* __restrict__ up_bhh,
    const float* __restrict__ down_wih, const float* __restrict__ down_whh,
    const float* __restrict__ down_bih, const float* __restrict__ down_bhh,
    const float* __restrict__ obs_w, const float* __restrict__ obs_b,
    const float* __restrict__ out_w, const float* __restrict__ out_b,
    float* __restrict__ out, int B) {
  __shared__ float sx[TPB * 19];   // input staging  (19456 B)
  __shared__ float sout[TPB * 7];  // output staging (7168 B)

  const int tid = threadIdx.x;
  const int base = blockIdx.x * TPB;
  const int rows = min(TPB, B - base);

  // ---- stage x: coalesced float4 (full blocks) ----
  if (rows == TPB) {
    const float4* src = (const float4*)(x + (size_t)base * 19);
    float4* dst = (float4*)sx;
#pragma unroll
    for (int i = tid; i < TPB * 19 / 4; i += TPB) dst[i] = src[i];
  } else {
    for (int i = tid; i < rows * 19; i += TPB) sx[i] = x[(size_t)base * 19 + i];
  }
  __syncthreads();

  if (tid < rows) {
    const float* xr = sx + tid * 19;  // stride 19 (odd) -> <=2-way bank alias, free
    float hu[14];                      // h_up history for the down pass

    // ---- up GRU, 7 steps (weights in SGPRs via uniform constant-index loads) ----
    {
      float h0 = 0.f, h1 = 0.f;
#pragma unroll
      for (int t = 0; t < 7; ++t) {
        GRU_STEP(up_wih, up_whh, up_bih, up_bhh, xr[5 + t], xr[12 + t], h0, h1);
        hu[2 * t] = h0;
        hu[2 * t + 1] = h1;
      }
    }

    // ---- obs linear: h = [obs(5) || h_last(2)] @ obs_w.T + obs_b ----
    float h0, h1;
    {
      float acc0 = obs_b[0], acc1 = obs_b[1];
#pragma unroll
      for (int k = 0; k < 5; ++k) {
        float c = xr[k];
        acc0 = fmaf(c, obs_w[k], acc0);
        acc1 = fmaf(c, obs_w[7 + k], acc1);
      }
      acc0 = fmaf(hu[12], obs_w[5], fmaf(hu[13], obs_w[6], acc0));
      acc1 = fmaf(hu[12], obs_w[12], fmaf(hu[13], obs_w[13], acc1));
      h0 = acc0;
      h1 = acc1;
    }

    // ---- down GRU, 7 steps + per-step output ----
    {
      const float ow0 = out_w[0], ow1 = out_w[1], ob = out_b[0];
#pragma unroll
      for (int t = 0; t < 7; ++t) {
        GRU_STEP(down_wih, down_whh, down_bih, down_bhh, hu[2 * t], hu[2 * t + 1],
                 h0, h1);
        sout[tid * 7 + t] = fmaf(ow0, h0, fmaf(ow1, h1, ob));
      }
    }
  }
  __syncthreads();

  // ---- coalesced float4 store ----
  if (rows == TPB) {
    float4* dst = (float4*)(out + (size_t)base * 7);
    const float4* src = (const float4*)sout;
#pragma unroll
    for (int i = tid; i < TPB * 7 / 4; i += TPB) dst[i] = src[i];
  } else {
    for (int i = tid; i < rows * 7; i += TPB) out[(size_t)base * 7 + i] = sout[i];
  }
}

extern "C" void kernel_launch(void* const* d_in, const int* in_sizes, int n_in,
                              void* d_out, int out_size, void* d_ws, size_t ws_size,
                              hipStream_t stream) {
  const float* x        = (const float*)d_in[0];
  const float* up_wih   = (const float*)d_in[1];
  const float* up_whh   = (const float*)d_in[2];
  const float* up_bih   = (const float*)d_in[3];
  const float* up_bhh   = (const float*)d_in[4];
  const float* down_wih = (const float*)d_in[5];
  const float* down_whh = (const float*)d_in[6];
  const float* down_bih = (const float*)d_in[7];
  const float* down_bhh = (const float*)d_in[8];
  const float* obs_w    = (const float*)d_in[9];
  const float* obs_b    = (const float*)d_in[10];
  const float* out_w    = (const float*)d_in[11];
  const float* out_b    = (const float*)d_in[12];
  float* out = (float*)d_out;

  const int B = in_sizes[0] / 19;
  const int blocks = (B + TPB - 1) / TPB;
  rec_policy_kernel<<<blocks, TPB, 0, stream>>>(
      x, up_wih, up_whh, up_bih, up_bhh, down_wih, down_whh, down_bih, down_bhh,
      obs_w, obs_b, out_w, out_b, out, B);
}

// Round 2
// 155.820 us; speedup vs baseline: 1.0022x; 1.0022x over previous
//
#include <hip/hip_runtime.h>

#define TPB 256
#define L2E 1.4426950408889634f  // log2(e)

__device__ __forceinline__ float fast_rcp(float x) { return __builtin_amdgcn_rcpf(x); }
__device__ __forceinline__ float exp2_fast(float x) { return __builtin_amdgcn_exp2f(x); }
// s = -log2e * (gate preactivation)  ->  sigma(p) = 1/(1+2^s)
__device__ __forceinline__ float sigm2(float s) { return fast_rcp(1.0f + exp2_fast(s)); }
// y = 2*log2e * a  ->  tanh(a) = 1 - 2/(2^y + 1)
__device__ __forceinline__ float tanh2(float y) {
  return fmaf(-2.0f, fast_rcp(exp2_fast(y) + 1.0f), 1.0f);
}

// GRU weights with the transcendental range-reduction constants pre-folded:
//   r,z gate rows scaled by -log2e (sigmoid: sigma(p) = rcp(1+exp2(-p*log2e)))
//   n gate rows scaled by +2*log2e (tanh(a) = 1 - 2*rcp(exp2(2a*log2e)+1))
// This removes the v_mul that __expf() would emit per transcendental.
struct GruW {
  float wrz[8], urz[8], brz[4];
  float wn[4], un[4], bin[2], bhn[2];
};

__device__ __forceinline__ void load_gru(const float* __restrict__ wih,
                                         const float* __restrict__ whh,
                                         const float* __restrict__ bih,
                                         const float* __restrict__ bhh, GruW& g) {
#pragma unroll
  for (int i = 0; i < 8; ++i) {
    g.wrz[i] = wih[i] * (-L2E);
    g.urz[i] = whh[i] * (-L2E);
  }
#pragma unroll
  for (int i = 0; i < 4; ++i) {
    g.brz[i] = (bih[i] + bhh[i]) * (-L2E);   // bih+bhh leaves the per-step path
    g.wn[i] = wih[8 + i] * (2.0f * L2E);
    g.un[i] = whh[8 + i] * (2.0f * L2E);
  }
#pragma unroll
  for (int i = 0; i < 2; ++i) {
    g.bin[i] = bih[4 + i] * (2.0f * L2E);
    g.bhn[i] = bhh[4 + i] * (2.0f * L2E);
  }
}

// One GRU step. FIRST=true specializes h==0 (first up-step): the whh terms and
// z*h vanish; the compiler cannot fold fmaf(w,0,b) itself without fast-math.
// h-update is h = n*(1-z) + z*h with (1-z), z*h computed while n is in flight,
// so only one fma trails the tanh on the critical path.
template <bool FIRST>
__device__ __forceinline__ void gru_step(const GruW& g, float x0, float x1,
                                         float& h0, float& h1) {
  float pr0 = fmaf(g.wrz[0], x0, fmaf(g.wrz[1], x1, g.brz[0]));
  float pr1 = fmaf(g.wrz[2], x0, fmaf(g.wrz[3], x1, g.brz[1]));
  float pz0 = fmaf(g.wrz[4], x0, fmaf(g.wrz[5], x1, g.brz[2]));
  float pz1 = fmaf(g.wrz[6], x0, fmaf(g.wrz[7], x1, g.brz[3]));
  float gin0 = fmaf(g.wn[0], x0, fmaf(g.wn[1], x1, g.bin[0]));
  float gin1 = fmaf(g.wn[2], x0, fmaf(g.wn[3], x1, g.bin[1]));
  float sr0, sr1, sz0, sz1, ghn0, ghn1;
  if constexpr (FIRST) {
    sr0 = pr0; sr1 = pr1; sz0 = pz0; sz1 = pz1;
    ghn0 = g.bhn[0]; ghn1 = g.bhn[1];
  } else {
    sr0 = fmaf(g.urz[0], h0, fmaf(g.urz[1], h1, pr0));
    sr1 = fmaf(g.urz[2], h0, fmaf(g.urz[3], h1, pr1));
    sz0 = fmaf(g.urz[4], h0, fmaf(g.urz[5], h1, pz0));
    sz1 = fmaf(g.urz[6], h0, fmaf(g.urz[7], h1, pz1));
    ghn0 = fmaf(g.un[0], h0, fmaf(g.un[1], h1, g.bhn[0]));
    ghn1 = fmaf(g.un[2], h0, fmaf(g.un[3], h1, g.bhn[1]));
  }
  float r0 = sigm2(sr0), r1 = sigm2(sr1);
  float z0 = sigm2(sz0), z1 = sigm2(sz1);
  float n0 = tanh2(fmaf(r0, ghn0, gin0));
  float n1 = tanh2(fmaf(r1, ghn1, gin1));
  float omz0 = 1.0f - z0, omz1 = 1.0f - z1;
  if constexpr (FIRST) {
    h0 = n0 * omz0;
    h1 = n1 * omz1;
  } else {
    float zh0 = z0 * h0, zh1 = z1 * h1;
    h0 = fmaf(n0, omz0, zh0);
    h1 = fmaf(n1, omz1, zh1);
  }
}

__global__ __launch_bounds__(TPB) void rec_policy_kernel(
    const float* __restrict__ x,
    const float* __restrict__ up_wih, const float* __restrict__ up_whh,
    const float* __restrict__ up_bih, const float* __restrict__ up_bhh,
    const float* __restrict__ down_wih, const float* __restrict__ down_whh,
    const float* __restrict__ down_bih, const float* __restrict__ down_bhh,
    const float* __restrict__ obs_w, const float* __restrict__ obs_b,
    const float* __restrict__ out_w, const float* __restrict__ out_b,
    float* __restrict__ out, int B) {
  __shared__ float sx[TPB * 19];  // input staging only (19456 B -> LDS no longer caps occupancy)

  const int tid = threadIdx.x;
  const int base = blockIdx.x * TPB;
  const int rows = min(TPB, B - base);

  // ---- stage x: coalesced float4 (full blocks) ----
  if (rows == TPB) {
    const float4* src = (const float4*)(x + (size_t)base * 19);
    float4* dst = (float4*)sx;
    for (int i = tid; i < TPB * 19 / 4; i += TPB) dst[i] = src[i];
  } else {
    for (int i = tid; i < rows * 19; i += TPB) sx[i] = x[(size_t)base * 19 + i];
  }
  __syncthreads();

  if (tid < rows) {
    const float* xr = sx + tid * 19;  // stride 19 (odd) -> <=2-way bank alias, free
    float hu[14];                     // h_up history for the down pass

    // ---- up GRU, 7 steps ----
    float h0, h1;
    {
      GruW ug;
      load_gru(up_wih, up_whh, up_bih, up_bhh, ug);
      gru_step<true>(ug, xr[5], xr[12], h0, h1);
      hu[0] = h0;
      hu[1] = h1;
#pragma unroll
      for (int t = 1; t < 7; ++t) {
        gru_step<false>(ug, xr[5 + t], xr[12 + t], h0, h1);
        hu[2 * t] = h0;
        hu[2 * t + 1] = h1;
      }
    }

    // ---- obs linear: h = [obs(5) || h_last(2)] @ obs_w.T + obs_b ----
    {
      float acc0 = obs_b[0], acc1 = obs_b[1];
#pragma unroll
      for (int k = 0; k < 5; ++k) {
        float c = xr[k];
        acc0 = fmaf(c, obs_w[k], acc0);
        acc1 = fmaf(c, obs_w[7 + k], acc1);
      }
      acc0 = fmaf(hu[12], obs_w[5], fmaf(hu[13], obs_w[6], acc0));
      acc1 = fmaf(hu[12], obs_w[12], fmaf(hu[13], obs_w[13], acc1));
      h0 = acc0;
      h1 = acc1;
    }

    // ---- down GRU, 7 steps + direct per-step store (no LDS, no 2nd barrier) ----
    {
      GruW dg;
      load_gru(down_wih, down_whh, down_bih, down_bhh, dg);
      const float ow0 = out_w[0], ow1 = out_w[1], ob = out_b[0];
      float* orow = out + ((size_t)base + tid) * 7;
#pragma unroll
      for (int t = 0; t < 7; ++t) {
        gru_step<false>(dg, hu[2 * t], hu[2 * t + 1], h0, h1);
        orow[t] = fmaf(ow0, h0, fmaf(ow1, h1, ob));
      }
    }
  }
}

extern "C" void kernel_launch(void* const* d_in, const int* in_sizes, int n_in,
                              void* d_out, int out_size, void* d_ws, size_t ws_size,
                              hipStream_t stream) {
  const float* x        = (const float*)d_in[0];
  const float* up_wih   = (const float*)d_in[1];
  const float* up_whh   = (const float*)d_in[2];
  const float* up_bih   = (const float*)d_in[3];
  const float* up_bhh   = (const float*)d_in[4];
  const float* down_wih = (const float*)d_in[5];
  const float* down_whh = (const float*)d_in[6];
  const float* down_bih = (const float*)d_in[7];
  const float* down_bhh = (const float*)d_in[8];
  const float* obs_w    = (const float*)d_in[9];
  const float* obs_b    = (const float*)d_in[10];
  const float* out_w    = (const float*)d_in[11];
  const float* out_b    = (const float*)d_in[12];
  float* out = (float*)d_out;

  const int B = in_sizes[0] / 19;
  const int blocks = (B + TPB - 1) / TPB;
  rec_policy_kernel<<<blocks, TPB, 0, stream>>>(
      x, up_wih, up_whh, up_bih, up_bhh, down_wih, down_whh, down_bih, down_bhh,
      obs_w, obs_b, out_w, out_b, out, B);
}